// Round 9
// baseline (489.688 us; speedup 1.0000x reference)
//
#include <hip/hip_runtime.h>

// LSTMForecaster: B=2048, S=512, IN=1, H=64, OUT=72, 2 LSTM layers + FC.
// Round 7 kernel (2nd resubmit after infra timeouts): BT=4, grid=512 ->
// 2 blocks/CU for TLP (one block's VALU/activation overlaps the other's
// MFMA/barrier). Full 64-lane activation spread: permlane32_swap +
// shfl_xor(16) + cndmask -> exactly 1 state/thread. fp16 MFMA single-term,
// exp2-direct activations, bias in C-init.

#define BATCH 2048
#define SEQ   512
#define HIDN  64
#define NOUT  72
#define BT    4
#define NT    512
#define L2E   1.4426950408889634f

typedef _Float16 f16x8 __attribute__((ext_vector_type(8)));
typedef float    f32x4 __attribute__((ext_vector_type(4)));

__device__ __forceinline__ float fast_rcp(float x){ return __builtin_amdgcn_rcpf(x); }
__device__ __forceinline__ float exp2_hw(float x){ float r; asm("v_exp_f32 %0, %1" : "=v"(r) : "v"(x)); return r; }
__device__ __forceinline__ float exp2_neg_hw(float x){ float r; asm("v_exp_f32 %0, -%1" : "=v"(r) : "v"(x)); return r; }
// input pre-scaled by log2e: sigmoid(x) = 1/(1+2^-s)
__device__ __forceinline__ float sigm2(float s){ return fast_rcp(1.f + exp2_neg_hw(s)); }
// input pre-scaled by 2*log2e: tanh(x) = 1 - 2/(2^s+1)
__device__ __forceinline__ float tanh2(float s){ return fmaf(-2.f, fast_rcp(exp2_hw(s) + 1.f), 1.f); }

// after this: result = [a.lanes0-31 | b.lanes0-31]
__device__ __forceinline__ float swap_pick(float a, float b){
    unsigned ua = __float_as_uint(a), ub = __float_as_uint(b);
    asm volatile("v_permlane32_swap_b32 %0, %1" : "+v"(ua), "+v"(ub));
    return __uint_as_float(ua);
}

__global__ __launch_bounds__(NT, 4)
void lstm2_mfma_kernel(const float* __restrict__ x,     // [B,S]
                       const float* __restrict__ wih0,  // [256,1]
                       const float* __restrict__ whh0,  // [256,64]
                       const float* __restrict__ bih0,
                       const float* __restrict__ bhh0,
                       const float* __restrict__ wih1,  // [256,64]
                       const float* __restrict__ whh1,  // [256,64]
                       const float* __restrict__ bih1,
                       const float* __restrict__ bhh1,
                       const float* __restrict__ fcw,   // [72,64]
                       const float* __restrict__ fcb,
                       float* __restrict__ out)         // [B,72]
{
    const int t    = threadIdx.x;
    const int lane = t & 63;
    const int w    = t >> 6;      // wave 0..7
    const int wq   = w & 3;       // hid-block within layer
    const int lyr  = w >> 2;      // 0 or 1
    const int l15  = lane & 15;
    const int lg   = lane >> 4;   // 0..3
    const int b0   = blockIdx.x * BT;
    const int hidb = wq * 16;

    __shared__ float x_sb[SEQ][BT];                       // 8 KB [s][b]
    __shared__ __align__(16) _Float16 fragA[2][4][32][8]; // [buf][kc][slot][e] 4 KB
    __shared__ float h_fc[BT][HIDN + 1];

    // ---- B-fragments (weights) single fp16, pre-scaled by gate scale ----
    //  gates i,f,o scaled by log2e; gate g (tanh) by 2*log2e.
    f16x8 bw[4][4];
    float bsum[4], wx[4];
    #pragma unroll
    for (int q = 0; q < 4; ++q) {
        const float sc = (q == 2) ? (2.f * L2E) : L2E;
        const int c = q*64 + hidb + l15;     // gate unit within layer
        if (lyr == 0) {
            #pragma unroll
            for (int kc = 0; kc < 2; ++kc) {
                const float* src = whh0 + c*HIDN + kc*32 + lg*8;
                f16x8 v;
                #pragma unroll
                for (int e = 0; e < 8; ++e) v[e] = (_Float16)(src[e] * sc);
                bw[q][kc] = v;
            }
            bsum[q] = (bih0[c] + bhh0[c]) * sc;
            wx[q]   = wih0[c] * sc;
        } else {
            #pragma unroll
            for (int kc = 0; kc < 4; ++kc) {
                const float* src = (kc < 2) ? (wih1 + c*HIDN + kc*32 + lg*8)
                                            : (whh1 + c*HIDN + (kc-2)*32 + lg*8);
                f16x8 v;
                #pragma unroll
                for (int e = 0; e < 8; ++e) v[e] = (_Float16)(src[e] * sc);
                bw[q][kc] = v;
            }
            bsum[q] = (bih1[c] + bhh1[c]) * sc;
            wx[q]   = 0.f;
        }
    }

    // ---- stage x (transposed [s][b]); zero fragA ----
    for (int i = t; i < BT * SEQ; i += NT) {
        int b = i >> 9, s = i & (SEQ - 1);
        x_sb[s][b] = x[(size_t)(b0 + b) * SEQ + s];
    }
    {
        unsigned* fz = (unsigned*)fragA;   // 4096 B = 1024 dwords
        for (int i = t; i < 1024; i += NT) fz[i] = 0u;
    }
    __syncthreads();

    // 1 state per thread: row srow = lane>>4 (0..3), hid hh = hidb + (lane&15)
    const int srow = lane >> 4;
    const int hh   = hidb + l15;
    const int kcs  = lyr * 2 + (hh >> 5);      // fragA kc slot for h writes
    const int eW   = hh & 7;
    const int g5   = (hh >> 3) & 3;
    const int slot_rd = lg * 8 + (lane & 7);   // slots 4..7 of each group stay 0
    float cst = 0.f;

    #pragma unroll 1
    for (int k = 0; k <= SEQ; ++k) {
        const int buf = k & 1, nbuf = buf ^ 1;

        // ---- GEMM: C-init = scaled bias; single fp16 term ----
        f32x4 acc[4];
        #pragma unroll
        for (int q = 0; q < 4; ++q) acc[q] = f32x4{bsum[q], bsum[q], bsum[q], bsum[q]};

        if (lyr == 0) {
            f16x8 a0 = *(const f16x8*)&fragA[buf][0][slot_rd][0];
            f16x8 a1 = *(const f16x8*)&fragA[buf][1][slot_rd][0];
            #pragma unroll
            for (int q = 0; q < 4; ++q) {
                acc[q] = __builtin_amdgcn_mfma_f32_16x16x32_f16(a0, bw[q][0], acc[q], 0, 0, 0);
                acc[q] = __builtin_amdgcn_mfma_f32_16x16x32_f16(a1, bw[q][1], acc[q], 0, 0, 0);
            }
        } else {
            f16x8 a[4];
            #pragma unroll
            for (int kc = 0; kc < 4; ++kc)
                a[kc] = *(const f16x8*)&fragA[buf][kc][slot_rd][0];
            #pragma unroll
            for (int kc = 0; kc < 4; ++kc) {
                #pragma unroll
                for (int q = 0; q < 4; ++q)
                    acc[q] = __builtin_amdgcn_mfma_f32_16x16x32_f16(a[kc], bw[q][kc], acc[q], 0, 0, 0);
            }
        }

        // ---- activation + state update: spread to all 64 lanes, 1 state each
        //  C/D layout: col = lane&15, row = (lane>>4)*4 + reg. Rows 0-3 only
        //  (lanes 0-15). Spread: permlane32_swap pairs regs (0,2),(1,3), then
        //  shfl_xor(16) + cndmask gives lane L -> row L>>4, col L&15.
        const bool do_state = lyr ? (k > 0) : (k < SEQ);
        if (do_state) {
            float g4[4];
            #pragma unroll
            for (int q = 0; q < 4; ++q) {
                float t0  = swap_pick(acc[q][0], acc[q][2]);  // rows 0 / 2
                float t1  = swap_pick(acc[q][1], acc[q][3]);  // rows 1 / 3
                float t1s = __shfl_xor(t1, 16);
                g4[q] = (lane & 16) ? t1s : t0;
            }
            float pi = g4[0], pf = g4[1], pg = g4[2], po = g4[3];
            if (lyr == 0) {
                float xv = x_sb[k][srow];
                pi = fmaf(wx[0], xv, pi); pf = fmaf(wx[1], xv, pf);
                pg = fmaf(wx[2], xv, pg); po = fmaf(wx[3], xv, po);
            }
            float iv = sigm2(pi), fv = sigm2(pf), gv = tanh2(pg), ov = sigm2(po);
            cst = fmaf(fv, cst, iv * gv);
            float h = ov * tanh2(cst * (2.f * L2E));
            fragA[nbuf][kcs][g5*8 + srow][eW] = (_Float16)h;
            if (lyr == 1 && k == SEQ) h_fc[srow][hh] = h;
        }
        __syncthreads();
    }

    // ---- FC: out = h1_final @ fc_w^T + fc_b ----
    for (int idx = t; idx < BT * NOUT; idx += NT) {
        int b = idx / NOUT, o = idx - b * NOUT;
        float a = fcb[o];
        #pragma unroll
        for (int j = 0; j < HIDN; ++j) a = fmaf(h_fc[b][j], fcw[o * HIDN + j], a);
        out[(size_t)(b0 + b) * NOUT + o] = a;
    }
}

extern "C" void kernel_launch(void* const* d_in, const int* in_sizes, int n_in,
                              void* d_out, int out_size, void* d_ws, size_t ws_size,
                              hipStream_t stream) {
    const float* x    = (const float*)d_in[0];
    const float* wih0 = (const float*)d_in[1];
    const float* whh0 = (const float*)d_in[2];
    const float* bih0 = (const float*)d_in[3];
    const float* bhh0 = (const float*)d_in[4];
    const float* wih1 = (const float*)d_in[5];
    const float* whh1 = (const float*)d_in[6];
    const float* bih1 = (const float*)d_in[7];
    const float* bhh1 = (const float*)d_in[8];
    const float* fcw  = (const float*)d_in[9];
    const float* fcb  = (const float*)d_in[10];
    float* out = (float*)d_out;

    dim3 grid(BATCH / BT);   // 512 blocks -> 2 per CU
    dim3 block(NT);
    hipLaunchKernelGGL(lstm2_mfma_kernel, grid, block, 0, stream,
                       x, wih0, whh0, bih0, bhh0, wih1, whh1, bih1, bhh1,
                       fcw, fcb, out);
}

// Round 12
// 440.191 us; speedup vs baseline: 1.1124x; 1.1124x over previous
//
#include <hip/hip_runtime.h>

// LSTMForecaster: B=2048, S=512, IN=1, H=64, OUT=72, 2 LSTM layers + FC.
// Round 12: round-6 dataflow (verified 362us) with NT=1024 (16 waves =
// 4/SIMD). Wave pair (v, v+8) duplicates round-6 wave v's MFMA (pipe was
// only 24.5% busy); half = w>>3 selects which of the wave's two states it
// finalizes -> activation chain per lane halves, 4 waves/SIMD hide the
// MFMA->permlane->exp dependency chains. In-register spread, 1 barrier/iter.
// fp16 MFMA single-term, exp2-direct activations, bias in C-init.

#define BATCH 2048
#define SEQ   512
#define HIDN  64
#define NOUT  72
#define BT    8
#define NT    1024
#define L2E   1.4426950408889634f

typedef _Float16 f16x8 __attribute__((ext_vector_type(8)));
typedef float    f32x4 __attribute__((ext_vector_type(4)));

__device__ __forceinline__ float fast_rcp(float x){ return __builtin_amdgcn_rcpf(x); }
__device__ __forceinline__ float exp2_hw(float x){ float r; asm("v_exp_f32 %0, %1" : "=v"(r) : "v"(x)); return r; }
__device__ __forceinline__ float exp2_neg_hw(float x){ float r; asm("v_exp_f32 %0, -%1" : "=v"(r) : "v"(x)); return r; }
// input pre-scaled by log2e: sigmoid(x) = 1/(1+2^-s)
__device__ __forceinline__ float sigm2(float s){ return fast_rcp(1.f + exp2_neg_hw(s)); }
// input pre-scaled by 2*log2e: tanh(x) = 1 - 2/(2^s+1)
__device__ __forceinline__ float tanh2(float s){ return fmaf(-2.f, fast_rcp(exp2_hw(s) + 1.f), 1.f); }

// result = [a.lanes0-31 | b.lanes0-31]
__device__ __forceinline__ float swap_pick(float a, float b){
    unsigned ua = __float_as_uint(a), ub = __float_as_uint(b);
    asm volatile("v_permlane32_swap_b32 %0, %1" : "+v"(ua), "+v"(ub));
    return __uint_as_float(ua);
}

__global__ __launch_bounds__(NT, 4)
void lstm2_mfma_kernel(const float* __restrict__ x,     // [B,S]
                       const float* __restrict__ wih0,  // [256,1]
                       const float* __restrict__ whh0,  // [256,64]
                       const float* __restrict__ bih0,
                       const float* __restrict__ bhh0,
                       const float* __restrict__ wih1,  // [256,64]
                       const float* __restrict__ whh1,  // [256,64]
                       const float* __restrict__ bih1,
                       const float* __restrict__ bhh1,
                       const float* __restrict__ fcw,   // [72,64]
                       const float* __restrict__ fcb,
                       float* __restrict__ out)         // [B,72]
{
    const int t    = threadIdx.x;
    const int lane = t & 63;
    const int w    = t >> 6;      // wave 0..15
    const int v    = w & 7;       // round-6 wave role
    const int half = w >> 3;      // which of the 2 states this wave finalizes
    const int wq   = v & 3;       // hid-block within layer
    const int lyr  = v >> 2;      // 0 or 1
    const int l15  = lane & 15;
    const int lg   = lane >> 4;   // 0..3
    const int b0   = blockIdx.x * BT;
    const int hidb = wq * 16;

    __shared__ float x_sb[SEQ][BT];                       // 16 KB [s][b]
    __shared__ __align__(16) _Float16 fragA[2][4][32][8]; // [buf][kc][slot][e] 4 KB
    __shared__ float h_fc[BT][HIDN + 1];

    // ---- B-fragments (weights) single fp16, pre-scaled by gate scale ----
    //  gates i,f,o scaled by log2e; gate g (tanh) by 2*log2e.
    //  Identical for both halves of a wave pair (duplicated MFMA).
    f16x8 bw[4][4];
    float bsum[4], wx[4];
    #pragma unroll
    for (int q = 0; q < 4; ++q) {
        const float sc = (q == 2) ? (2.f * L2E) : L2E;
        const int c = q * 64 + hidb + l15;     // gate unit within layer
        if (lyr == 0) {
            #pragma unroll
            for (int kc = 0; kc < 2; ++kc) {
                const float* src = whh0 + c * HIDN + kc * 32 + lg * 8;
                f16x8 vv;
                #pragma unroll
                for (int e = 0; e < 8; ++e) vv[e] = (_Float16)(src[e] * sc);
                bw[q][kc] = vv;
            }
            bsum[q] = (bih0[c] + bhh0[c]) * sc;
            wx[q]   = wih0[c] * sc;
        } else {
            #pragma unroll
            for (int kc = 0; kc < 4; ++kc) {
                const float* src = (kc < 2) ? (wih1 + c * HIDN + kc * 32 + lg * 8)
                                            : (whh1 + c * HIDN + (kc - 2) * 32 + lg * 8);
                f16x8 vv;
                #pragma unroll
                for (int e = 0; e < 8; ++e) vv[e] = (_Float16)(src[e] * sc);
                bw[q][kc] = vv;
            }
            bsum[q] = (bih1[c] + bhh1[c]) * sc;
            wx[q]   = 0.f;
        }
    }

    // ---- stage x (transposed [s][b]); zero fragA ----
    for (int i = t; i < BT * SEQ; i += NT) {
        int b = i >> 9, s = i & (SEQ - 1);
        x_sb[s][b] = x[(size_t)(b0 + b) * SEQ + s];
    }
    {
        unsigned* fz = (unsigned*)fragA;   // 4096 B = 1024 dwords
        if (t < 1024) fz[t] = 0u;
    }
    __syncthreads();

    // state rows by lane quadrant (validated round-6 mapping):
    //  bb = {0,4,2,6}; this wave finalizes row = bb + half.
    const int bb   = ((lane >> 4) & 1) * 4 + (lane >> 5) * 2;
    const int row  = bb + half;
    const int hh   = hidb + l15;               // hid index this lane updates
    const int kcs  = lyr * 2 + (hh >> 5);      // fragA kc slot for h writes
    const int eW   = hh & 7;
    const int g5   = (hh >> 3) & 3;
    const int slot_rd = lg * 8 + (lane & 7);
    float cst = 0.f;                           // cell state for (row, hh)

    #pragma unroll 1
    for (int k = 0; k <= SEQ; ++k) {
        const int buf = k & 1, nbuf = buf ^ 1;

        // ---- GEMM: C-init = scaled bias; single fp16 term (round-6) ----
        f32x4 acc[4];
        #pragma unroll
        for (int q = 0; q < 4; ++q) acc[q] = f32x4{bsum[q], bsum[q], bsum[q], bsum[q]};

        if (lyr == 0) {
            f16x8 a0 = *(const f16x8*)&fragA[buf][0][slot_rd][0];
            f16x8 a1 = *(const f16x8*)&fragA[buf][1][slot_rd][0];
            #pragma unroll
            for (int q = 0; q < 4; ++q) {
                acc[q] = __builtin_amdgcn_mfma_f32_16x16x32_f16(a0, bw[q][0], acc[q], 0, 0, 0);
                acc[q] = __builtin_amdgcn_mfma_f32_16x16x32_f16(a1, bw[q][1], acc[q], 0, 0, 0);
            }
        } else {
            f16x8 a[4];
            #pragma unroll
            for (int kc = 0; kc < 4; ++kc)
                a[kc] = *(const f16x8*)&fragA[buf][kc][slot_rd][0];
            #pragma unroll
            for (int kc = 0; kc < 4; ++kc) {
                #pragma unroll
                for (int q = 0; q < 4; ++q)
                    acc[q] = __builtin_amdgcn_mfma_f32_16x16x32_f16(a[kc], bw[q][kc], acc[q], 0, 0, 0);
            }
        }

        // ---- activation: this wave's ONE state per lane ----
        //  half=0: rows bb   via swap_pick(acc[0], acc[2])  (round-6 "row A")
        //  half=1: rows bb+1 via swap_pick(acc[1], acc[3])  (round-6 "row B")
        const bool do_state = lyr ? (k > 0) : (k < SEQ);
        if (do_state) {
            float g4[4];
            if (half == 0) {
                #pragma unroll
                for (int q = 0; q < 4; ++q) g4[q] = swap_pick(acc[q][0], acc[q][2]);
            } else {
                #pragma unroll
                for (int q = 0; q < 4; ++q) g4[q] = swap_pick(acc[q][1], acc[q][3]);
            }
            float pi = g4[0], pf = g4[1], pg = g4[2], po = g4[3];
            if (lyr == 0) {
                float xv = x_sb[k][row];
                pi = fmaf(wx[0], xv, pi); pf = fmaf(wx[1], xv, pf);
                pg = fmaf(wx[2], xv, pg); po = fmaf(wx[3], xv, po);
            }
            float iv = sigm2(pi), fv = sigm2(pf), gv = tanh2(pg), ov = sigm2(po);
            cst = fmaf(fv, cst, iv * gv);
            float h = ov * tanh2(cst * (2.f * L2E));
            fragA[nbuf][kcs][g5 * 8 + row][eW] = (_Float16)h;
            if (lyr == 1 && k == SEQ) h_fc[row][hh] = h;
        }
        __syncthreads();
    }

    // ---- FC: out = h1_final @ fc_w^T + fc_b ----
    for (int idx = t; idx < BT * NOUT; idx += NT) {
        int b = idx / NOUT, o = idx - b * NOUT;
        float a = fcb[o];
        #pragma unroll
        for (int j = 0; j < HIDN; ++j) a = fmaf(h_fc[b][j], fcw[o * HIDN + j], a);
        out[(size_t)(b0 + b) * NOUT + o] = a;
    }
}

extern "C" void kernel_launch(void* const* d_in, const int* in_sizes, int n_in,
                              void* d_out, int out_size, void* d_ws, size_t ws_size,
                              hipStream_t stream) {
    const float* x    = (const float*)d_in[0];
    const float* wih0 = (const float*)d_in[1];
    const float* whh0 = (const float*)d_in[2];
    const float* bih0 = (const float*)d_in[3];
    const float* bhh0 = (const float*)d_in[4];
    const float* wih1 = (const float*)d_in[5];
    const float* whh1 = (const float*)d_in[6];
    const float* bih1 = (const float*)d_in[7];
    const float* bhh1 = (const float*)d_in[8];
    const float* fcw  = (const float*)d_in[9];
    const float* fcb  = (const float*)d_in[10];
    float* out = (float*)d_out;

    dim3 grid(BATCH / BT);   // 256 blocks -> 1 per CU, 16 waves each
    dim3 block(NT);
    hipLaunchKernelGGL(lstm2_mfma_kernel, grid, block, 0, stream,
                       x, wih0, whh0, bih0, bhh0, wih1, whh1, bih1, bhh1,
                       fcw, fcb, out);
}

// Round 14
// 399.396 us; speedup vs baseline: 1.2261x; 1.1021x over previous
//
#include <hip/hip_runtime.h>

// LSTMForecaster: B=2048, S=512, IN=1, H=64, OUT=72, 2 LSTM layers + FC.
// Round 13 (resubmit after infra timeout): round-6 structure (verified best,
// 362us) + x/bias folded INTO the GEMM via a 5th kc slot (A col k64=x(k),
// k65=1.0; B rows wih0*sc, bias*sc) and persistent zero-C first MFMA (no
// per-iter acc init). Removes ~28 VALU inst/wave-iter, moves work to the
// 24.5%-busy MFMA pipe. fp16 MFMA single-term, exp2-direct activations.

#define BATCH 2048
#define SEQ   512
#define HIDN  64
#define NOUT  72
#define BT    8
#define NT    512
#define L2E   1.4426950408889634f

typedef _Float16 f16x8 __attribute__((ext_vector_type(8)));
typedef float    f32x4 __attribute__((ext_vector_type(4)));

__device__ __forceinline__ float fast_rcp(float x){ return __builtin_amdgcn_rcpf(x); }
__device__ __forceinline__ float exp2_hw(float x){ float r; asm("v_exp_f32 %0, %1" : "=v"(r) : "v"(x)); return r; }
__device__ __forceinline__ float exp2_neg_hw(float x){ float r; asm("v_exp_f32 %0, -%1" : "=v"(r) : "v"(x)); return r; }
// input pre-scaled by log2e: sigmoid(x) = 1/(1+2^-s)
__device__ __forceinline__ float sigm2(float s){ return fast_rcp(1.f + exp2_neg_hw(s)); }
// input pre-scaled by 2*log2e: tanh(x) = 1 - 2/(2^s+1)
__device__ __forceinline__ float tanh2(float s){ return fmaf(-2.f, fast_rcp(exp2_hw(s) + 1.f), 1.f); }

// result = [a.lanes0-31 | b.lanes0-31]
__device__ __forceinline__ float swap_pick(float a, float b){
    unsigned ua = __float_as_uint(a), ub = __float_as_uint(b);
    asm volatile("v_permlane32_swap_b32 %0, %1" : "+v"(ua), "+v"(ub));
    return __uint_as_float(ua);
}

__global__ __launch_bounds__(NT, 2)
void lstm2_mfma_kernel(const float* __restrict__ x,     // [B,S]
                       const float* __restrict__ wih0,  // [256,1]
                       const float* __restrict__ whh0,  // [256,64]
                       const float* __restrict__ bih0,
                       const float* __restrict__ bhh0,
                       const float* __restrict__ wih1,  // [256,64]
                       const float* __restrict__ whh1,  // [256,64]
                       const float* __restrict__ bih1,
                       const float* __restrict__ bhh1,
                       const float* __restrict__ fcw,   // [72,64]
                       const float* __restrict__ fcb,
                       float* __restrict__ out)         // [B,72]
{
    const int t    = threadIdx.x;
    const int lane = t & 63;
    const int w    = t >> 6;      // wave 0..7
    const int wq   = w & 3;       // hid-block within layer
    const int lyr  = w >> 2;      // 0 or 1
    const int l15  = lane & 15;
    const int lg   = lane >> 4;   // 0..3
    const int b0   = blockIdx.x * BT;
    const int hidb = wq * 16;

    __shared__ float x_sb[SEQ][BT];                       // 16 KB [s][b]
    __shared__ __align__(16) _Float16 fragA[2][5][32][8]; // [buf][kc][slot][e] 5 KB; kc4 = x/bias col
    __shared__ float h_fc[BT][HIDN + 1];

    // state rows by lane quadrant (verified mapping): bb = {0,4,2,6}
    const int bb = ((lane >> 4) & 1) * 4 + (lane >> 5) * 2;

    // ---- B-fragments (weights) single fp16, pre-scaled by gate scale ----
    //  gates i,f,o scaled by log2e; gate g (tanh) by 2*log2e.
    //  kc4: k_local0 = wih0*sc (l0) / 0 (l1), k_local1 = bias_sum*sc, rest 0.
    f16x8 bw[4][5];
    #pragma unroll
    for (int q = 0; q < 4; ++q) {
        const float sc = (q == 2) ? (2.f * L2E) : L2E;
        const int c = q * 64 + hidb + l15;     // gate unit within layer
        if (lyr == 0) {
            #pragma unroll
            for (int kc = 0; kc < 2; ++kc) {
                const float* src = whh0 + c * HIDN + kc * 32 + lg * 8;
                f16x8 v;
                #pragma unroll
                for (int e = 0; e < 8; ++e) v[e] = (_Float16)(src[e] * sc);
                bw[q][kc] = v;
            }
        } else {
            #pragma unroll
            for (int kc = 0; kc < 4; ++kc) {
                const float* src = (kc < 2) ? (wih1 + c * HIDN + kc * 32 + lg * 8)
                                            : (whh1 + c * HIDN + (kc - 2) * 32 + lg * 8);
                f16x8 v;
                #pragma unroll
                for (int e = 0; e < 8; ++e) v[e] = (_Float16)(src[e] * sc);
                bw[q][kc] = v;
            }
        }
        {   // kc4 (x + bias column)
            f16x8 v;
            #pragma unroll
            for (int e = 0; e < 8; ++e) v[e] = (_Float16)0.f;
            if (lg == 0) {
                float wxv = lyr ? 0.f : wih0[c] * sc;
                float bsv = lyr ? (bih1[c] + bhh1[c]) * sc
                                : (bih0[c] + bhh0[c]) * sc;
                v[0] = (_Float16)wxv;
                v[1] = (_Float16)bsv;
            }
            bw[q][4] = v;
        }
    }

    // ---- stage x (transposed [s][b]); zero fragA ----
    for (int i = t; i < BT * SEQ; i += NT) {
        int b = i >> 9, s = i & (SEQ - 1);
        x_sb[s][b] = x[(size_t)(b0 + b) * SEQ + s];
    }
    {
        unsigned* fz = (unsigned*)fragA;   // 2*5*32*8*2B = 5120 B = 1280 dwords
        for (int i = t; i < 1280; i += NT) fz[i] = 0u;
    }
    __syncthreads();   // zero-init complete before kc4 seed writes

    // seed buf0 kc4 with x(0) and 1.0 (rows from global, no x_sb dependency order issue)
    if (w == 0 && l15 == 0) {
        union { _Float16 h[2]; unsigned u; } pk;
        pk.h[1] = (_Float16)1.0f;
        pk.h[0] = (_Float16)x[(size_t)(b0 + bb) * SEQ + 0];
        *(unsigned*)&fragA[0][4][bb][0] = pk.u;
        pk.h[0] = (_Float16)x[(size_t)(b0 + bb + 1) * SEQ + 0];
        *(unsigned*)&fragA[0][4][bb + 1][0] = pk.u;
    }
    __syncthreads();

    const int hh   = hidb + l15;               // hid index this lane updates
    const int kcs  = lyr * 2 + (hh >> 5);      // fragA kc slot for h writes
    const int eW   = hh & 7;
    const int g5   = (hh >> 3) & 3;
    const int slot_rd = lg * 8 + (lane & 7);
    float c0 = 0.f, c1 = 0.f;                  // cell state rows bb, bb+1
    const f32x4 z4 = {0.f, 0.f, 0.f, 0.f};     // persistent zero C-init

    #pragma unroll 1
    for (int k = 0; k <= SEQ; ++k) {
        const int buf = k & 1, nbuf = buf ^ 1;

        // ---- GEMM: first MFMA takes z4 as C; bias+x arrive via kc4 ----
        f32x4 acc[4];
        if (lyr == 0) {
            f16x8 a0 = *(const f16x8*)&fragA[buf][0][slot_rd][0];
            f16x8 a1 = *(const f16x8*)&fragA[buf][1][slot_rd][0];
            f16x8 a4 = *(const f16x8*)&fragA[buf][4][slot_rd][0];
            #pragma unroll
            for (int q = 0; q < 4; ++q) {
                acc[q] = __builtin_amdgcn_mfma_f32_16x16x32_f16(a0, bw[q][0], z4,     0, 0, 0);
                acc[q] = __builtin_amdgcn_mfma_f32_16x16x32_f16(a1, bw[q][1], acc[q], 0, 0, 0);
                acc[q] = __builtin_amdgcn_mfma_f32_16x16x32_f16(a4, bw[q][4], acc[q], 0, 0, 0);
            }
        } else {
            f16x8 a[5];
            #pragma unroll
            for (int kc = 0; kc < 5; ++kc)
                a[kc] = *(const f16x8*)&fragA[buf][kc][slot_rd][0];
            #pragma unroll
            for (int q = 0; q < 4; ++q) {
                acc[q] = __builtin_amdgcn_mfma_f32_16x16x32_f16(a[0], bw[q][0], z4, 0, 0, 0);
                #pragma unroll
                for (int kc = 1; kc < 5; ++kc)
                    acc[q] = __builtin_amdgcn_mfma_f32_16x16x32_f16(a[kc], bw[q][kc], acc[q], 0, 0, 0);
            }
        }

        // ---- next-step x column into fragA[nbuf][4] (4 lanes of wave 0) ----
        if (w == 0 && l15 == 0 && (k + 1) < SEQ) {
            union { _Float16 h[2]; unsigned u; } pk;
            pk.h[1] = (_Float16)1.0f;
            pk.h[0] = (_Float16)x_sb[k + 1][bb];
            *(unsigned*)&fragA[nbuf][4][bb][0] = pk.u;
            pk.h[0] = (_Float16)x_sb[k + 1][bb + 1];
            *(unsigned*)&fragA[nbuf][4][bb + 1][0] = pk.u;
        }

        // ---- activation + state update (bias/x already inside acc) ----
        const bool do_state = lyr ? (k > 0) : (k < SEQ);
        if (do_state) {
            float ga[4], gb[4];
            #pragma unroll
            for (int q = 0; q < 4; ++q) {
                ga[q] = swap_pick(acc[q][0], acc[q][2]);   // rows {0,4,2,6}
                gb[q] = swap_pick(acc[q][1], acc[q][3]);   // rows {1,5,3,7}
            }
            // row A (bb)
            {
                float iv = sigm2(ga[0]), fv = sigm2(ga[1]), gv = tanh2(ga[2]), ov = sigm2(ga[3]);
                c0 = fmaf(fv, c0, iv * gv);
                float h = ov * tanh2(c0 * (2.f * L2E));
                fragA[nbuf][kcs][g5 * 8 + bb][eW] = (_Float16)h;
                if (lyr == 1 && k == SEQ) h_fc[bb][hh] = h;
            }
            // row B (bb+1)
            {
                float iv = sigm2(gb[0]), fv = sigm2(gb[1]), gv = tanh2(gb[2]), ov = sigm2(gb[3]);
                c1 = fmaf(fv, c1, iv * gv);
                float h = ov * tanh2(c1 * (2.f * L2E));
                fragA[nbuf][kcs][g5 * 8 + bb + 1][eW] = (_Float16)h;
                if (lyr == 1 && k == SEQ) h_fc[bb + 1][hh] = h;
            }
        }
        __syncthreads();
    }

    // ---- FC: out = h1_final @ fc_w^T + fc_b ----
    for (int idx = t; idx < BT * NOUT; idx += NT) {
        int b = idx / NOUT, o = idx - b * NOUT;
        float a = fcb[o];
        #pragma unroll
        for (int j = 0; j < HIDN; ++j) a = fmaf(h_fc[b][j], fcw[o * HIDN + j], a);
        out[(size_t)(b0 + b) * NOUT + o] = a;
    }
}

extern "C" void kernel_launch(void* const* d_in, const int* in_sizes, int n_in,
                              void* d_out, int out_size, void* d_ws, size_t ws_size,
                              hipStream_t stream) {
    const float* x    = (const float*)d_in[0];
    const float* wih0 = (const float*)d_in[1];
    const float* whh0 = (const float*)d_in[2];
    const float* bih0 = (const float*)d_in[3];
    const float* bhh0 = (const float*)d_in[4];
    const float* wih1 = (const float*)d_in[5];
    const float* whh1 = (const float*)d_in[6];
    const float* bih1 = (const float*)d_in[7];
    const float* bhh1 = (const float*)d_in[8];
    const float* fcw  = (const float*)d_in[9];
    const float* fcb  = (const float*)d_in[10];
    float* out = (float*)d_out;

    dim3 grid(BATCH / BT);   // 256 blocks -> 1 per CU, 8 waves each
    dim3 block(NT);
    hipLaunchKernelGGL(lstm2_mfma_kernel, grid, block, 0, stream,
                       x, wih0, whh0, bih0, bhh0, wih1, whh1, bih1, bhh1,
                       fcw, fcb, out);
}